// Round 4
// baseline (1653.759 us; speedup 1.0000x reference)
//
#include <hip/hip_runtime.h>

// 3-layer sparse conv, gather formulation, zero atomics.
// R4: conv3 rewritten as c-split x4 within 4-lane groups (shared row, shfl
// reduce) — restores the 27-offset L2 locality the R3 k-split destroyed and
// raises occupancy x4. conv2 j-split folded into a linear grid with bijective
// XCD-chunked swizzle so all 4 j-quarters of the same rows share one XCD's L2.

#define TPB 256

// m204 bijective XCD-chunk swizzle: hardware round-robins bid%8 across XCDs;
// remap so each XCD owns a contiguous chunk of logical work ids.
__device__ __forceinline__ int xcd_chunk(int bid, int nwg) {
  int q = nwg >> 3, r = nwg & 7;
  int xcd = bid & 7, idx = bid >> 3;
  int base = (xcd < r) ? xcd * (q + 1) : r * (q + 1) + (xcd - r) * q;
  return base + idx;
}

__global__ void __launch_bounds__(TPB)
k_build(const int* __restrict__ mi, const int* __restrict__ mo,
        int* __restrict__ tbl, int L, int n_out) {
  int k = blockIdx.y;
  int p = blockIdx.x * TPB + threadIdx.x;
  if (p >= L) return;
  int out = mo[(size_t)k * L + p];
  bool valid = out < n_out;                 // pads point at dummy row n_out
  if (__ballot(valid) == 0ull) return;      // pads are a contiguous tail
  if (valid) tbl[(size_t)k * n_out + out] = mi[(size_t)k * L + p];
}

// conv1: 8 -> 64, 27 offsets. lane = output row, blockIdx.y = j-half (32 ch).
__global__ void __launch_bounds__(TPB)
k_conv1(const float* __restrict__ x, const float* __restrict__ W1,
        const float* __restrict__ b1, const int* __restrict__ t1,
        float* __restrict__ h1, int n1) {
  int r = blockIdx.x * TPB + threadIdx.x;
  if (r >= n1) return;
  int j0 = blockIdx.y * 32;
  float acc[32];
#pragma unroll
  for (int j = 0; j < 32; ++j) acc[j] = 0.f;
#pragma unroll 1
  for (int k = 0; k < 27; ++k) {
    int idx = t1[(size_t)k * n1 + r];
    bool v = idx >= 0;
    if (__ballot(v) == 0ull) continue;
    const float4* xr = (const float4*)(x + (size_t)(v ? idx : 0) * 8);
    float4 a = xr[0], b = xr[1];
    if (!v) { a = make_float4(0.f,0.f,0.f,0.f); b = make_float4(0.f,0.f,0.f,0.f); }
    float xv[8] = {a.x, a.y, a.z, a.w, b.x, b.y, b.z, b.w};
    const float* __restrict__ Wk = W1 + (size_t)k * 512 + j0;   // (8,64) col-slice
#pragma unroll
    for (int i = 0; i < 8; ++i)
#pragma unroll
      for (int j = 0; j < 32; ++j)
        acc[j] = fmaf(xv[i], Wk[i * 64 + j], acc[j]);
  }
  float4* yr = (float4*)(h1 + (size_t)r * 64 + j0);
#pragma unroll
  for (int q = 0; q < 8; ++q) {
    float4 o;
    o.x = fmaxf(acc[4*q+0] + b1[j0+4*q+0], 0.f);
    o.y = fmaxf(acc[4*q+1] + b1[j0+4*q+1], 0.f);
    o.z = fmaxf(acc[4*q+2] + b1[j0+4*q+2], 0.f);
    o.w = fmaxf(acc[4*q+3] + b1[j0+4*q+3], 0.f);
    yr[q] = o;
  }
}

// conv2: 64 -> 64, 8 offsets. Linear grid: block -> (row chunk, j-quarter),
// XCD-chunk swizzled so the 4 j-quarters of one row range share an XCD L2.
__global__ void __launch_bounds__(TPB)
k_conv2(const float* __restrict__ h1, const float* __restrict__ W2,
        const float* __restrict__ b2, const int* __restrict__ t2,
        float* __restrict__ h2, int n1, int n2, int nwg) {
  int b = xcd_chunk(blockIdx.x, nwg);
  int jq = b & 3, xb = b >> 2;
  int r = xb * TPB + threadIdx.x;
  if (r >= n2) return;
  int j0 = jq * 16;
  float acc[16];
#pragma unroll
  for (int j = 0; j < 16; ++j) acc[j] = 0.f;
#pragma unroll 1
  for (int k = 0; k < 8; ++k) {
    int idx = t2[(size_t)k * n2 + r];
    int row = idx >= 0 ? idx : n1;          // zero row
    const float4* xr = (const float4*)(h1 + (size_t)row * 64);
    const float* __restrict__ Wk = W2 + (size_t)k * 4096 + j0;  // (64,64) col-slice
#pragma unroll 4
    for (int c = 0; c < 16; ++c) {
      float4 xv = xr[c];
#pragma unroll
      for (int j = 0; j < 16; ++j) {
        acc[j] = fmaf(xv.x, Wk[(4*c+0)*64 + j], acc[j]);
        acc[j] = fmaf(xv.y, Wk[(4*c+1)*64 + j], acc[j]);
        acc[j] = fmaf(xv.z, Wk[(4*c+2)*64 + j], acc[j]);
        acc[j] = fmaf(xv.w, Wk[(4*c+3)*64 + j], acc[j]);
      }
    }
  }
  float4* yr = (float4*)(h2 + (size_t)r * 64 + j0);
#pragma unroll
  for (int q = 0; q < 4; ++q) {
    float4 o;
    o.x = fmaxf(acc[4*q+0] + b2[j0+4*q+0], 0.f);
    o.y = fmaxf(acc[4*q+1] + b2[j0+4*q+1], 0.f);
    o.z = fmaxf(acc[4*q+2] + b2[j0+4*q+2], 0.f);
    o.w = fmaxf(acc[4*q+3] + b2[j0+4*q+3], 0.f);
    yr[q] = o;
  }
}

// conv3: 64 -> 8, 27 offsets. 4 lanes per output row (q = c-quarter): each
// lane gathers its 64B quarter of the h2 row (consecutive lanes -> consecutive
// addresses), accumulates 16c x 8j, then 2-round shfl_xor reduce; lanes q<2
// store float4 halves. All 27 k per thread -> L2 row reuse intact.
__global__ void __launch_bounds__(TPB)
k_conv3(const float* __restrict__ h2, const float* __restrict__ W3,
        const float* __restrict__ b3, const int* __restrict__ t3,
        float* __restrict__ out, int n2, int nwg) {
  int b = xcd_chunk(blockIdx.x, nwg);
  int r = b * (TPB / 4) + (threadIdx.x >> 2);
  int q = threadIdx.x & 3;
  if (r >= n2) return;
  float acc[8];
#pragma unroll
  for (int j = 0; j < 8; ++j) acc[j] = 0.f;
#pragma unroll 1
  for (int k = 0; k < 27; ++k) {
    int idx = t3[(size_t)k * n2 + r];       // 4-lane broadcast read
    int row = idx >= 0 ? idx : n2;          // zero row
    const float4* xr = (const float4*)(h2 + (size_t)row * 64 + q * 16);
    float4 c0 = xr[0], c1 = xr[1], c2 = xr[2], c3 = xr[3];
    float h[16] = {c0.x, c0.y, c0.z, c0.w, c1.x, c1.y, c1.z, c1.w,
                   c2.x, c2.y, c2.z, c2.w, c3.x, c3.y, c3.z, c3.w};
    const float* __restrict__ Wk = W3 + (size_t)k * 512 + q * 128;  // rows q*16..
#pragma unroll
    for (int u = 0; u < 16; ++u) {
      float4 w0 = *(const float4*)(Wk + u * 8);
      float4 w1 = *(const float4*)(Wk + u * 8 + 4);
      acc[0] = fmaf(h[u], w0.x, acc[0]);
      acc[1] = fmaf(h[u], w0.y, acc[1]);
      acc[2] = fmaf(h[u], w0.z, acc[2]);
      acc[3] = fmaf(h[u], w0.w, acc[3]);
      acc[4] = fmaf(h[u], w1.x, acc[4]);
      acc[5] = fmaf(h[u], w1.y, acc[5]);
      acc[6] = fmaf(h[u], w1.z, acc[6]);
      acc[7] = fmaf(h[u], w1.w, acc[7]);
    }
  }
#pragma unroll
  for (int m = 1; m <= 2; m <<= 1)
#pragma unroll
    for (int j = 0; j < 8; ++j) acc[j] += __shfl_xor(acc[j], m);
  if (q < 2) {
    float4 o;
    o.x = acc[q*4+0] + b3[q*4+0];
    o.y = acc[q*4+1] + b3[q*4+1];
    o.z = acc[q*4+2] + b3[q*4+2];
    o.w = acc[q*4+3] + b3[q*4+3];
    *(float4*)(out + (size_t)r * 8 + q * 4) = o;
  }
}

extern "C" void kernel_launch(void* const* d_in, const int* in_sizes, int n_in,
                              void* d_out, int out_size, void* d_ws, size_t ws_size,
                              hipStream_t stream) {
  const float* feats = (const float*)d_in[0];
  const float* W1 = (const float*)d_in[1];
  const float* b1 = (const float*)d_in[2];
  const float* W2 = (const float*)d_in[3];
  const float* b2 = (const float*)d_in[4];
  const float* W3 = (const float*)d_in[5];
  const float* b3 = (const float*)d_in[6];
  const int* m1i = (const int*)d_in[7];
  const int* m1o = (const int*)d_in[8];
  const int* m2i = (const int*)d_in[9];
  const int* m2o = (const int*)d_in[10];
  const int* m3i = (const int*)d_in[11];
  const int* m3o = (const int*)d_in[12];

  int n1 = in_sizes[0] / 8;
  int L1 = in_sizes[7] / 27;
  int L2 = in_sizes[9] / 8;
  int L3 = in_sizes[11] / 27;
  int n2 = out_size / 8;

  // Workspace layout (t1 aliases the y2 region: t1 dead before conv2 writes y2)
  char* ws = (char*)d_ws;
  size_t y1_bytes = (size_t)(n1 + 1) * 64 * sizeof(float);
  size_t y2_bytes = (size_t)(n2 + 1) * 64 * sizeof(float);
  size_t t1_bytes = (size_t)27 * n1 * sizeof(int);
  size_t reg1_bytes = y2_bytes > t1_bytes ? y2_bytes : t1_bytes;
  float* y1 = (float*)ws;                              // h1: (n1+1) x 64
  float* y2 = (float*)(ws + y1_bytes);                 // h2: (n2+1) x 64
  int* t1 = (int*)(ws + y1_bytes);                     // alias (27 x n1)
  int* t2 = (int*)(ws + y1_bytes + reg1_bytes);        // 8 x n2
  int* t3 = (int*)(ws + y1_bytes + reg1_bytes + (size_t)8 * n2 * sizeof(int));

  hipMemsetAsync(t1, 0xFF, t1_bytes, stream);
  hipMemsetAsync(t2, 0xFF, (size_t)8 * n2 * sizeof(int), stream);
  hipMemsetAsync(t3, 0xFF, (size_t)27 * n2 * sizeof(int), stream);

  k_build<<<dim3((L1 + TPB - 1) / TPB, 27), TPB, 0, stream>>>(m1i, m1o, t1, L1, n1);
  k_build<<<dim3((L2 + TPB - 1) / TPB, 8), TPB, 0, stream>>>(m2i, m2o, t2, L2, n2);
  k_build<<<dim3((L3 + TPB - 1) / TPB, 27), TPB, 0, stream>>>(m3i, m3o, t3, L3, n2);

  k_conv1<<<dim3((n1 + TPB - 1) / TPB, 2), TPB, 0, stream>>>(feats, W1, b1, t1, y1, n1);

  // zero rows for invalid gathers (y2's zero row lives inside the t1 alias
  // region, so write it only after conv1 has consumed t1)
  hipMemsetAsync(y1 + (size_t)n1 * 64, 0, 64 * sizeof(float), stream);
  hipMemsetAsync(y2 + (size_t)n2 * 64, 0, 64 * sizeof(float), stream);

  int nb2 = ((n2 + TPB - 1) / TPB) * 4;
  k_conv2<<<nb2, TPB, 0, stream>>>(y1, W2, b2, t2, y2, n1, n2, nb2);

  int nb3 = (n2 + (TPB / 4) - 1) / (TPB / 4);
  k_conv3<<<nb3, TPB, 0, stream>>>(y2, W3, b3, t3, (float*)d_out, n2, nb3);
}

// Round 5
// 649.639 us; speedup vs baseline: 2.5457x; 2.5457x over previous
//
#include <hip/hip_runtime.h>

// 3-layer sparse conv, gather formulation, zero atomics.
// R5: conv3 back to row-per-thread with wave-uniform W3 (s_load; R4's per-lane
// W loads + no MLP were the 1216us stall) + 2-deep register double-buffer:
// rolling scalar idx prefetch (no reg-array dynamic indexing) and row k+1
// streaming in under row k's 512 FMAs.

#define TPB 256

// m204 bijective XCD-chunk swizzle
__device__ __forceinline__ int xcd_chunk(int bid, int nwg) {
  int q = nwg >> 3, r = nwg & 7;
  int xcd = bid & 7, idx = bid >> 3;
  int base = (xcd < r) ? xcd * (q + 1) : r * (q + 1) + (xcd - r) * q;
  return base + idx;
}

__global__ void __launch_bounds__(TPB)
k_build(const int* __restrict__ mi, const int* __restrict__ mo,
        int* __restrict__ tbl, int L, int n_out) {
  int k = blockIdx.y;
  int p = blockIdx.x * TPB + threadIdx.x;
  if (p >= L) return;
  int out = mo[(size_t)k * L + p];
  bool valid = out < n_out;                 // pads point at dummy row n_out
  if (__ballot(valid) == 0ull) return;      // pads are a contiguous tail
  if (valid) tbl[(size_t)k * n_out + out] = mi[(size_t)k * L + p];
}

// conv1: 8 -> 64, 27 offsets. lane = output row, blockIdx.y = j-half (32 ch).
__global__ void __launch_bounds__(TPB)
k_conv1(const float* __restrict__ x, const float* __restrict__ W1,
        const float* __restrict__ b1, const int* __restrict__ t1,
        float* __restrict__ h1, int n1) {
  int r = blockIdx.x * TPB + threadIdx.x;
  if (r >= n1) return;
  int j0 = blockIdx.y * 32;
  float acc[32];
#pragma unroll
  for (int j = 0; j < 32; ++j) acc[j] = 0.f;
#pragma unroll 1
  for (int k = 0; k < 27; ++k) {
    int idx = t1[(size_t)k * n1 + r];
    bool v = idx >= 0;
    if (__ballot(v) == 0ull) continue;
    const float4* xr = (const float4*)(x + (size_t)(v ? idx : 0) * 8);
    float4 a = xr[0], b = xr[1];
    if (!v) { a = make_float4(0.f,0.f,0.f,0.f); b = make_float4(0.f,0.f,0.f,0.f); }
    float xv[8] = {a.x, a.y, a.z, a.w, b.x, b.y, b.z, b.w};
    const float* __restrict__ Wk = W1 + (size_t)k * 512 + j0;   // (8,64) col-slice
#pragma unroll
    for (int i = 0; i < 8; ++i)
#pragma unroll
      for (int j = 0; j < 32; ++j)
        acc[j] = fmaf(xv[i], Wk[i * 64 + j], acc[j]);
  }
  float4* yr = (float4*)(h1 + (size_t)r * 64 + j0);
#pragma unroll
  for (int q = 0; q < 8; ++q) {
    float4 o;
    o.x = fmaxf(acc[4*q+0] + b1[j0+4*q+0], 0.f);
    o.y = fmaxf(acc[4*q+1] + b1[j0+4*q+1], 0.f);
    o.z = fmaxf(acc[4*q+2] + b1[j0+4*q+2], 0.f);
    o.w = fmaxf(acc[4*q+3] + b1[j0+4*q+3], 0.f);
    yr[q] = o;
  }
}

// conv2: 64 -> 64, 8 offsets. Linear grid: block -> (row chunk, j-quarter),
// XCD-chunk swizzled so the 4 j-quarters of one row range share an XCD L2.
__global__ void __launch_bounds__(TPB)
k_conv2(const float* __restrict__ h1, const float* __restrict__ W2,
        const float* __restrict__ b2, const int* __restrict__ t2,
        float* __restrict__ h2, int n1, int n2, int nwg) {
  int b = xcd_chunk(blockIdx.x, nwg);
  int jq = b & 3, xb = b >> 2;
  int r = xb * TPB + threadIdx.x;
  if (r >= n2) return;
  int j0 = jq * 16;
  float acc[16];
#pragma unroll
  for (int j = 0; j < 16; ++j) acc[j] = 0.f;
#pragma unroll 1
  for (int k = 0; k < 8; ++k) {
    int idx = t2[(size_t)k * n2 + r];
    int row = idx >= 0 ? idx : n1;          // zero row
    const float4* xr = (const float4*)(h1 + (size_t)row * 64);
    const float* __restrict__ Wk = W2 + (size_t)k * 4096 + j0;  // (64,64) col-slice
#pragma unroll 4
    for (int c = 0; c < 16; ++c) {
      float4 xv = xr[c];
#pragma unroll
      for (int j = 0; j < 16; ++j) {
        acc[j] = fmaf(xv.x, Wk[(4*c+0)*64 + j], acc[j]);
        acc[j] = fmaf(xv.y, Wk[(4*c+1)*64 + j], acc[j]);
        acc[j] = fmaf(xv.z, Wk[(4*c+2)*64 + j], acc[j]);
        acc[j] = fmaf(xv.w, Wk[(4*c+3)*64 + j], acc[j]);
      }
    }
  }
  float4* yr = (float4*)(h2 + (size_t)r * 64 + j0);
#pragma unroll
  for (int q = 0; q < 4; ++q) {
    float4 o;
    o.x = fmaxf(acc[4*q+0] + b2[j0+4*q+0], 0.f);
    o.y = fmaxf(acc[4*q+1] + b2[j0+4*q+1], 0.f);
    o.z = fmaxf(acc[4*q+2] + b2[j0+4*q+2], 0.f);
    o.w = fmaxf(acc[4*q+3] + b2[j0+4*q+3], 0.f);
    yr[q] = o;
  }
}

// conv3: 64 -> 8, 27 offsets, row per thread. W3 wave-uniform (s_load).
// 2-deep register double-buffer: row k+1's 16 float4 loads issue under row
// k's 512 FMAs; idx prefetched as rolling scalars (no dynamic reg-array).
#define LOADROW3(BUF, IDX) {                                          \
  const float4* xp_ = (const float4*)(h2 + (size_t)(IDX) * 64);       \
  _Pragma("unroll") for (int c_ = 0; c_ < 16; ++c_) BUF[c_] = xp_[c_]; }

#define FMAROW3(BUF, KK) {                                            \
  const float* Wk_ = W3 + (size_t)(KK) * 512;                         \
  _Pragma("unroll") for (int c_ = 0; c_ < 16; ++c_) {                 \
    float4 xv_ = BUF[c_];                                             \
    float hv_[4] = {xv_.x, xv_.y, xv_.z, xv_.w};                      \
    _Pragma("unroll") for (int u_ = 0; u_ < 4; ++u_)                  \
      _Pragma("unroll") for (int j_ = 0; j_ < 8; ++j_)                \
        acc[j_] = fmaf(hv_[u_], Wk_[(4*c_+u_)*8 + j_], acc[j_]); } }

__global__ void __launch_bounds__(TPB)
k_conv3(const float* __restrict__ h2, const float* __restrict__ W3,
        const float* __restrict__ b3, const int* __restrict__ t3,
        float* __restrict__ out, int n2, int nwg) {
  int b = xcd_chunk(blockIdx.x, nwg);
  int r = b * TPB + threadIdx.x;
  if (r >= n2) return;
  float acc[8];
#pragma unroll
  for (int j = 0; j < 8; ++j) acc[j] = b3[j];

  // rolling idx prefetch (invalid -> zero row n2)
  int i0 = t3[r];                 i0 = i0 >= 0 ? i0 : n2;   // row for k=0
  int i1 = t3[(size_t)n2 + r];    i1 = i1 >= 0 ? i1 : n2;   // row for k=1
  float4 A[16], B[16];
  LOADROW3(A, i0);
#pragma unroll 1
  for (int k = 0; k < 26; k += 2) {
    LOADROW3(B, i1);                                   // row k+1 under FMA(k)
    int i2 = t3[(size_t)(k + 2) * n2 + r];  i2 = i2 >= 0 ? i2 : n2;
    FMAROW3(A, k);
    LOADROW3(A, i2);                                   // row k+2 under FMA(k+1)
    int k3 = k + 3 < 26 ? k + 3 : 26;                  // clamp (branchless, uniform)
    int i3 = t3[(size_t)k3 * n2 + r];       i3 = i3 >= 0 ? i3 : n2;
    FMAROW3(B, k + 1);
    i1 = i3;
  }
  FMAROW3(A, 26);
  float4* o = (float4*)(out + (size_t)r * 8);
  o[0] = make_float4(acc[0], acc[1], acc[2], acc[3]);
  o[1] = make_float4(acc[4], acc[5], acc[6], acc[7]);
}

extern "C" void kernel_launch(void* const* d_in, const int* in_sizes, int n_in,
                              void* d_out, int out_size, void* d_ws, size_t ws_size,
                              hipStream_t stream) {
  const float* feats = (const float*)d_in[0];
  const float* W1 = (const float*)d_in[1];
  const float* b1 = (const float*)d_in[2];
  const float* W2 = (const float*)d_in[3];
  const float* b2 = (const float*)d_in[4];
  const float* W3 = (const float*)d_in[5];
  const float* b3 = (const float*)d_in[6];
  const int* m1i = (const int*)d_in[7];
  const int* m1o = (const int*)d_in[8];
  const int* m2i = (const int*)d_in[9];
  const int* m2o = (const int*)d_in[10];
  const int* m3i = (const int*)d_in[11];
  const int* m3o = (const int*)d_in[12];

  int n1 = in_sizes[0] / 8;
  int L1 = in_sizes[7] / 27;
  int L2 = in_sizes[9] / 8;
  int L3 = in_sizes[11] / 27;
  int n2 = out_size / 8;

  // Workspace layout (t1 aliases the y2 region: t1 dead before conv2 writes y2)
  char* ws = (char*)d_ws;
  size_t y1_bytes = (size_t)(n1 + 1) * 64 * sizeof(float);
  size_t y2_bytes = (size_t)(n2 + 1) * 64 * sizeof(float);
  size_t t1_bytes = (size_t)27 * n1 * sizeof(int);
  size_t reg1_bytes = y2_bytes > t1_bytes ? y2_bytes : t1_bytes;
  float* y1 = (float*)ws;                              // h1: (n1+1) x 64
  float* y2 = (float*)(ws + y1_bytes);                 // h2: (n2+1) x 64
  int* t1 = (int*)(ws + y1_bytes);                     // alias (27 x n1)
  int* t2 = (int*)(ws + y1_bytes + reg1_bytes);        // 8 x n2
  int* t3 = (int*)(ws + y1_bytes + reg1_bytes + (size_t)8 * n2 * sizeof(int));

  hipMemsetAsync(t1, 0xFF, t1_bytes, stream);
  hipMemsetAsync(t2, 0xFF, (size_t)8 * n2 * sizeof(int), stream);
  hipMemsetAsync(t3, 0xFF, (size_t)27 * n2 * sizeof(int), stream);

  k_build<<<dim3((L1 + TPB - 1) / TPB, 27), TPB, 0, stream>>>(m1i, m1o, t1, L1, n1);
  k_build<<<dim3((L2 + TPB - 1) / TPB, 8), TPB, 0, stream>>>(m2i, m2o, t2, L2, n2);
  k_build<<<dim3((L3 + TPB - 1) / TPB, 27), TPB, 0, stream>>>(m3i, m3o, t3, L3, n2);

  k_conv1<<<dim3((n1 + TPB - 1) / TPB, 2), TPB, 0, stream>>>(feats, W1, b1, t1, y1, n1);

  // zero rows for invalid gathers (y2's zero row lives inside the t1 alias
  // region, so write it only after conv1 has consumed t1)
  hipMemsetAsync(y1 + (size_t)n1 * 64, 0, 64 * sizeof(float), stream);
  hipMemsetAsync(y2 + (size_t)n2 * 64, 0, 64 * sizeof(float), stream);

  int nb2 = ((n2 + TPB - 1) / TPB) * 4;
  k_conv2<<<nb2, TPB, 0, stream>>>(y1, W2, b2, t2, y2, n1, n2, nb2);

  int nb3 = (n2 + TPB - 1) / TPB;
  k_conv3<<<nb3, TPB, 0, stream>>>(y2, W3, b3, t3, (float*)d_out, n2, nb3);
}

// Round 6
// 600.783 us; speedup vs baseline: 2.7527x; 1.0813x over previous
//
#include <hip/hip_runtime.h>

// 3-layer sparse conv, gather formulation, zero atomics.
// R6: conv3 = 64-row blocks, 4 waves k-split (k ≡ w mod 4), LDS reduce.
//  - all lanes of a wave share k -> W3 wave-uniform via readfirstlane -> s_load
//  - k-loop stays within one block/CU -> L2 row locality intact (R3 lesson)
//  - grid n2/64 * 4 waves -> ~4x the waves of row-per-thread (R5 lesson)

#define TPB 256

// m204 bijective XCD-chunk swizzle
__device__ __forceinline__ int xcd_chunk(int bid, int nwg) {
  int q = nwg >> 3, r = nwg & 7;
  int xcd = bid & 7, idx = bid >> 3;
  int base = (xcd < r) ? xcd * (q + 1) : r * (q + 1) + (xcd - r) * q;
  return base + idx;
}

__global__ void __launch_bounds__(TPB)
k_build(const int* __restrict__ mi, const int* __restrict__ mo,
        int* __restrict__ tbl, int L, int n_out) {
  int k = blockIdx.y;
  int p = blockIdx.x * TPB + threadIdx.x;
  if (p >= L) return;
  int out = mo[(size_t)k * L + p];
  bool valid = out < n_out;                 // pads point at dummy row n_out
  if (__ballot(valid) == 0ull) return;      // pads are a contiguous tail
  if (valid) tbl[(size_t)k * n_out + out] = mi[(size_t)k * L + p];
}

// conv1: 8 -> 64, 27 offsets. lane = output row, blockIdx.y = j-half (32 ch).
__global__ void __launch_bounds__(TPB)
k_conv1(const float* __restrict__ x, const float* __restrict__ W1,
        const float* __restrict__ b1, const int* __restrict__ t1,
        float* __restrict__ h1, int n1) {
  int r = blockIdx.x * TPB + threadIdx.x;
  if (r >= n1) return;
  int j0 = blockIdx.y * 32;
  float acc[32];
#pragma unroll
  for (int j = 0; j < 32; ++j) acc[j] = 0.f;
#pragma unroll 1
  for (int k = 0; k < 27; ++k) {
    int idx = t1[(size_t)k * n1 + r];
    bool v = idx >= 0;
    if (__ballot(v) == 0ull) continue;
    const float4* xr = (const float4*)(x + (size_t)(v ? idx : 0) * 8);
    float4 a = xr[0], b = xr[1];
    if (!v) { a = make_float4(0.f,0.f,0.f,0.f); b = make_float4(0.f,0.f,0.f,0.f); }
    float xv[8] = {a.x, a.y, a.z, a.w, b.x, b.y, b.z, b.w};
    const float* __restrict__ Wk = W1 + (size_t)k * 512 + j0;   // (8,64) col-slice
#pragma unroll
    for (int i = 0; i < 8; ++i)
#pragma unroll
      for (int j = 0; j < 32; ++j)
        acc[j] = fmaf(xv[i], Wk[i * 64 + j], acc[j]);
  }
  float4* yr = (float4*)(h1 + (size_t)r * 64 + j0);
#pragma unroll
  for (int q = 0; q < 8; ++q) {
    float4 o;
    o.x = fmaxf(acc[4*q+0] + b1[j0+4*q+0], 0.f);
    o.y = fmaxf(acc[4*q+1] + b1[j0+4*q+1], 0.f);
    o.z = fmaxf(acc[4*q+2] + b1[j0+4*q+2], 0.f);
    o.w = fmaxf(acc[4*q+3] + b1[j0+4*q+3], 0.f);
    yr[q] = o;
  }
}

// conv2: 64 -> 64, 8 offsets. Linear grid: block -> (row chunk, j-quarter),
// XCD-chunk swizzled so the 4 j-quarters of one row range share an XCD L2.
__global__ void __launch_bounds__(TPB)
k_conv2(const float* __restrict__ h1, const float* __restrict__ W2,
        const float* __restrict__ b2, const int* __restrict__ t2,
        float* __restrict__ h2, int n1, int n2, int nwg) {
  int b = xcd_chunk(blockIdx.x, nwg);
  int jq = b & 3, xb = b >> 2;
  int r = xb * TPB + threadIdx.x;
  if (r >= n2) return;
  int j0 = jq * 16;
  float acc[16];
#pragma unroll
  for (int j = 0; j < 16; ++j) acc[j] = 0.f;
#pragma unroll 1
  for (int k = 0; k < 8; ++k) {
    int idx = t2[(size_t)k * n2 + r];
    int row = idx >= 0 ? idx : n1;          // zero row
    const float4* xr = (const float4*)(h1 + (size_t)row * 64);
    const float* __restrict__ Wk = W2 + (size_t)k * 4096 + j0;  // (64,64) col-slice
#pragma unroll 4
    for (int c = 0; c < 16; ++c) {
      float4 xv = xr[c];
#pragma unroll
      for (int j = 0; j < 16; ++j) {
        acc[j] = fmaf(xv.x, Wk[(4*c+0)*64 + j], acc[j]);
        acc[j] = fmaf(xv.y, Wk[(4*c+1)*64 + j], acc[j]);
        acc[j] = fmaf(xv.z, Wk[(4*c+2)*64 + j], acc[j]);
        acc[j] = fmaf(xv.w, Wk[(4*c+3)*64 + j], acc[j]);
      }
    }
  }
  float4* yr = (float4*)(h2 + (size_t)r * 64 + j0);
#pragma unroll
  for (int q = 0; q < 4; ++q) {
    float4 o;
    o.x = fmaxf(acc[4*q+0] + b2[j0+4*q+0], 0.f);
    o.y = fmaxf(acc[4*q+1] + b2[j0+4*q+1], 0.f);
    o.z = fmaxf(acc[4*q+2] + b2[j0+4*q+2], 0.f);
    o.w = fmaxf(acc[4*q+3] + b2[j0+4*q+3], 0.f);
    yr[q] = o;
  }
}

// conv3: 64 -> 8, 27 offsets. Block = 64 output rows; wave w handles
// k ≡ w (mod 4) — lanes within a wave share k, so W3 stays SGPR (s_load,
// forced via readfirstlane). Partials reduced through padded LDS; b3 folded
// into the reduce; plain coalesced stores.
__global__ void __launch_bounds__(TPB)
k_conv3(const float* __restrict__ h2, const float* __restrict__ W3,
        const float* __restrict__ b3, const int* __restrict__ t3,
        float* __restrict__ out, int n2, int nwg) {
  __shared__ float red[4][64][9];           // 9-padded (9 coprime 32)
  int b = xcd_chunk(blockIdx.x, nwg);
  int w = __builtin_amdgcn_readfirstlane(threadIdx.x >> 6);  // wave id, SGPR
  int l = threadIdx.x & 63;
  int r = b * 64 + l;
  int rc = r < n2 ? r : n2 - 1;             // clamp: safe loads, store guarded
  float acc[8];
#pragma unroll
  for (int j = 0; j < 8; ++j) acc[j] = 0.f;
  int nk = (w < 3) ? 7 : 6;                 // k = w + 4*i, k < 27
  int idx = t3[(size_t)w * n2 + rc];        // prefetch i=0
#pragma unroll 1
  for (int i = 0; i < nk; ++i) {
    int k = w + 4 * i;
    int row = idx >= 0 ? idx : n2;          // zero row
    if (i + 1 < nk) idx = t3[(size_t)(k + 4) * n2 + rc];   // break 2-level chain
    const float4* xr = (const float4*)(h2 + (size_t)row * 64);
    const float* __restrict__ Wk = W3 + (size_t)k * 512;   // SGPR base (k uniform)
#pragma unroll
    for (int c = 0; c < 16; ++c) {
      float4 xv = xr[c];
      float hv[4] = {xv.x, xv.y, xv.z, xv.w};
#pragma unroll
      for (int u = 0; u < 4; ++u)
#pragma unroll
        for (int j = 0; j < 8; ++j)
          acc[j] = fmaf(hv[u], Wk[(4*c+u)*8 + j], acc[j]);
    }
  }
#pragma unroll
  for (int j = 0; j < 8; ++j) red[w][l][j] = acc[j];
  __syncthreads();
  // 512 outputs (64 rows x 8 ch); thread t handles t and t+256, coalesced.
#pragma unroll
  for (int t = threadIdx.x; t < 512; t += TPB) {
    int row = t >> 3, ch = t & 7;
    int g = b * 64 + row;
    if (g < n2) {
      float s = red[0][row][ch] + red[1][row][ch]
              + red[2][row][ch] + red[3][row][ch];
      out[(size_t)g * 8 + ch] = s + b3[ch];
    }
  }
}

extern "C" void kernel_launch(void* const* d_in, const int* in_sizes, int n_in,
                              void* d_out, int out_size, void* d_ws, size_t ws_size,
                              hipStream_t stream) {
  const float* feats = (const float*)d_in[0];
  const float* W1 = (const float*)d_in[1];
  const float* b1 = (const float*)d_in[2];
  const float* W2 = (const float*)d_in[3];
  const float* b2 = (const float*)d_in[4];
  const float* W3 = (const float*)d_in[5];
  const float* b3 = (const float*)d_in[6];
  const int* m1i = (const int*)d_in[7];
  const int* m1o = (const int*)d_in[8];
  const int* m2i = (const int*)d_in[9];
  const int* m2o = (const int*)d_in[10];
  const int* m3i = (const int*)d_in[11];
  const int* m3o = (const int*)d_in[12];

  int n1 = in_sizes[0] / 8;
  int L1 = in_sizes[7] / 27;
  int L2 = in_sizes[9] / 8;
  int L3 = in_sizes[11] / 27;
  int n2 = out_size / 8;

  // Workspace layout (t1 aliases the y2 region: t1 dead before conv2 writes y2)
  char* ws = (char*)d_ws;
  size_t y1_bytes = (size_t)(n1 + 1) * 64 * sizeof(float);
  size_t y2_bytes = (size_t)(n2 + 1) * 64 * sizeof(float);
  size_t t1_bytes = (size_t)27 * n1 * sizeof(int);
  size_t reg1_bytes = y2_bytes > t1_bytes ? y2_bytes : t1_bytes;
  float* y1 = (float*)ws;                              // h1: (n1+1) x 64
  float* y2 = (float*)(ws + y1_bytes);                 // h2: (n2+1) x 64
  int* t1 = (int*)(ws + y1_bytes);                     // alias (27 x n1)
  int* t2 = (int*)(ws + y1_bytes + reg1_bytes);        // 8 x n2
  int* t3 = (int*)(ws + y1_bytes + reg1_bytes + (size_t)8 * n2 * sizeof(int));

  hipMemsetAsync(t1, 0xFF, t1_bytes, stream);
  hipMemsetAsync(t2, 0xFF, (size_t)8 * n2 * sizeof(int), stream);
  hipMemsetAsync(t3, 0xFF, (size_t)27 * n2 * sizeof(int), stream);

  k_build<<<dim3((L1 + TPB - 1) / TPB, 27), TPB, 0, stream>>>(m1i, m1o, t1, L1, n1);
  k_build<<<dim3((L2 + TPB - 1) / TPB, 8), TPB, 0, stream>>>(m2i, m2o, t2, L2, n2);
  k_build<<<dim3((L3 + TPB - 1) / TPB, 27), TPB, 0, stream>>>(m3i, m3o, t3, L3, n2);

  k_conv1<<<dim3((n1 + TPB - 1) / TPB, 2), TPB, 0, stream>>>(feats, W1, b1, t1, y1, n1);

  // zero rows for invalid gathers (y2's zero row lives inside the t1 alias
  // region, so write it only after conv1 has consumed t1)
  hipMemsetAsync(y1 + (size_t)n1 * 64, 0, 64 * sizeof(float), stream);
  hipMemsetAsync(y2 + (size_t)n2 * 64, 0, 64 * sizeof(float), stream);

  int nb2 = ((n2 + TPB - 1) / TPB) * 4;
  k_conv2<<<nb2, TPB, 0, stream>>>(y1, W2, b2, t2, y2, n1, n2, nb2);

  int nb3 = (n2 + 63) / 64;
  k_conv3<<<nb3, TPB, 0, stream>>>(y2, W3, b3, t3, (float*)d_out, n2, nb3);
}